// Round 3
// baseline (372.975 us; speedup 1.0000x reference)
//
#include <hip/hip_runtime.h>
#include <utility>
#include <cstddef>
#include <cmath>

// ============================================================================
// Compile-time real-basis Wigner 3j (Clebsch-Gordan) tensors.
// Device code sees only literal constants -> fully static register indexing.
// ============================================================================
namespace cg {

struct FactTab { double f[24]; };
constexpr FactTab make_fact() {
  FactTab t{}; t.f[0] = 1.0;
  for (int i = 1; i < 24; ++i) t.f[i] = t.f[i-1] * (double)i;
  return t;
}
constexpr FactTab FT = make_fact();
constexpr double F(int n) { return FT.f[n]; }

constexpr double csqrt(double x) {
  if (x <= 0.0) return 0.0;
  double g = x > 1.0 ? x : 1.0;
  for (int i = 0; i < 200; ++i) {
    double ng = 0.5 * (g + x / g);
    if (ng >= g) break;
    g = ng;
  }
  return g;
}

struct T3 { double v[13][13][13]; };

constexpr T3 w3j_c(int l1, int l2, int l3) {
  T3 C{};
  const double tri = F(l1+l2-l3) * F(l1-l2+l3) * F(-l1+l2+l3) / F(l1+l2+l3+1);
  for (int m1 = -l1; m1 <= l1; ++m1) {
    for (int m2 = -l2; m2 <= l2; ++m2) {
      const int m3 = -m1 - m2;
      if (m3 < -l3 || m3 > l3) continue;
      const int e = l1 - l2 - m3;
      const double sign = (((e % 2) + 2) % 2) ? -1.0 : 1.0;
      const double pref = sign * csqrt(tri * F(l1+m1) * F(l1-m1) * F(l2+m2)
                                           * F(l2-m2) * F(l3+m3) * F(l3-m3));
      int t0 = 0;
      if (l2 - l3 - m1 > t0) t0 = l2 - l3 - m1;
      if (l1 - l3 + m2 > t0) t0 = l1 - l3 + m2;
      int t1 = l1 + l2 - l3;
      if (l1 - m1 < t1) t1 = l1 - m1;
      if (l2 + m2 < t1) t1 = l2 + m2;
      double s = 0.0;
      for (int t = t0; t <= t1; ++t) {
        const double term = 1.0 / (F(t) * F(l1+l2-l3-t) * F(l1-m1-t)
                                   * F(l2+m2-t) * F(l3-l2+m1+t) * F(l3-l1-m2+t));
        s += (t % 2) ? -term : term;
      }
      C.v[m1+l1][m2+l2][m3+l3] = pref * s;
    }
  }
  return C;
}

struct C2 { double re, im; };
constexpr C2 cmul(C2 a, C2 b) { return C2{a.re*b.re - a.im*b.im, a.re*b.im + a.im*b.re}; }

struct UCol { int n; int row[2]; C2 val[2]; };
constexpr UCol ucol(int l, int a) {
  UCol r{};
  const double s2 = csqrt(0.5);
  if (a == l) {
    r.n = 1; r.row[0] = l; r.val[0] = C2{1.0, 0.0};
  } else if (a > l) {
    const int m = a - l;
    const double sg = (m % 2) ? -1.0 : 1.0;
    r.n = 2;
    r.row[0] = l + m; r.val[0] = C2{sg * s2, 0.0};
    r.row[1] = l - m; r.val[1] = C2{0.0, -sg * s2};
  } else {
    const int m = l - a;
    r.n = 2;
    r.row[0] = l + m; r.val[0] = C2{s2, 0.0};
    r.row[1] = l - m; r.val[1] = C2{0.0, s2};
  }
  return r;
}

constexpr T3 to_real(const T3& Cc, int l1, int l2, int l3) {
  T3 R{};
  UCol U1[13]{}, U2[13]{}, U3[13]{};
  for (int a = 0; a < 2*l1+1; ++a) U1[a] = ucol(l1, a);
  for (int b = 0; b < 2*l2+1; ++b) U2[b] = ucol(l2, b);
  for (int c = 0; c < 2*l3+1; ++c) U3[c] = ucol(l3, c);
  for (int a = 0; a < 2*l1+1; ++a)
    for (int b = 0; b < 2*l2+1; ++b)
      for (int c = 0; c < 2*l3+1; ++c) {
        const double cv = Cc.v[a][b][c];
        if (cv == 0.0) continue;
        for (int ia = 0; ia < U1[a].n; ++ia)
          for (int jb = 0; jb < U2[b].n; ++jb)
            for (int kc = 0; kc < U3[c].n; ++kc) {
              C2 t = cmul(cmul(U1[a].val[ia], U2[b].val[jb]), U3[c].val[kc]);
              R.v[U1[a].row[ia]][U2[b].row[jb]][U3[c].row[kc]] += t.re * cv;
            }
      }
  return R;
}

struct Ent { short i, j, k; float v; };
constexpr int CAP = 1100;
template <int C> struct List { int n; Ent e[C]; };

constexpr List<CAP> make_list(const T3& R, int d1, int d2, int d3) {
  List<CAP> L{};
  for (int i = 0; i < d1; ++i)
    for (int j = 0; j < d2; ++j)
      for (int k = 0; k < d3; ++k) {
        const double v = R.v[i][j][k];
        if (v > 1e-10 || v < -1e-10) {
          L.e[L.n].i = (short)i; L.e[L.n].j = (short)j; L.e[L.n].k = (short)k;
          L.e[L.n].v = (float)v;
          L.n++;
        }
      }
  return L;
}

constexpr T3 CC444 = w3j_c(4,4,4);
constexpr T3 CC446 = w3j_c(4,4,6);
constexpr T3 CC464 = w3j_c(4,6,4);
constexpr T3 CC466 = w3j_c(4,6,6);
constexpr T3 CC644 = w3j_c(6,4,4);
constexpr T3 CC646 = w3j_c(6,4,6);
constexpr T3 CC664 = w3j_c(6,6,4);
constexpr T3 CC666 = w3j_c(6,6,6);

constexpr T3 CR444 = to_real(CC444, 4,4,4);
constexpr T3 CR446 = to_real(CC446, 4,4,6);
constexpr T3 CR464 = to_real(CC464, 4,6,4);
constexpr T3 CR466 = to_real(CC466, 4,6,6);
constexpr T3 CR644 = to_real(CC644, 6,4,4);
constexpr T3 CR646 = to_real(CC646, 6,4,6);
constexpr T3 CR664 = to_real(CC664, 6,6,4);
constexpr T3 CR666 = to_real(CC666, 6,6,6);

struct Tag444 { static constexpr List<CAP> L = make_list(CR444, 9, 9, 9);  };
struct Tag446 { static constexpr List<CAP> L = make_list(CR446, 9, 9, 13); };
struct Tag464 { static constexpr List<CAP> L = make_list(CR464, 9, 13, 9); };
struct Tag466 { static constexpr List<CAP> L = make_list(CR466, 9, 13, 13);};
struct Tag644 { static constexpr List<CAP> L = make_list(CR644, 13, 9, 9); };
struct Tag646 { static constexpr List<CAP> L = make_list(CR646, 13, 9, 13);};
struct Tag664 { static constexpr List<CAP> L = make_list(CR664, 13, 13, 9);};
struct Tag666 { static constexpr List<CAP> L = make_list(CR666, 13, 13, 13);};

template <class Tag, size_t... Es>
__device__ __forceinline__ void cg_apply_impl(const float* __restrict__ x,
                                              const float* __restrict__ y,
                                              float* __restrict__ acc,
                                              std::index_sequence<Es...>) {
  ((acc[(int)Tag::L.e[Es].k] +=
        Tag::L.e[Es].v * (x[(int)Tag::L.e[Es].i] * y[(int)Tag::L.e[Es].j])), ...);
}
template <class Tag>
__device__ __forceinline__ void cg_apply(const float* __restrict__ x,
                                         const float* __restrict__ y,
                                         float* __restrict__ acc) {
  cg_apply_impl<Tag>(x, y, acc, std::make_index_sequence<(size_t)Tag::L.n>{});
}

} // namespace cg

// ============================================================================
// Kernel 1: word-parallel 3x3 replicate-pad depthwise conv.
// One thread per WORD of nb (n*22 words). ~30 VGPR -> 8 waves/SIMD, gather
// latency hidden by TLP. All loads/stores coalesced.
// ============================================================================
__global__ __launch_bounds__(256) void conv_kernel(
    const float* __restrict__ f4, const float* __restrict__ f6,
    const float* __restrict__ sw,
    const int* __restrict__ Hp, const int* __restrict__ Wp,
    float* __restrict__ nb4, float* __restrict__ nb6) {
  const int H = Hp[0], W = Wp[0];
  const int n = H * W;
  const int n9 = n * 9;
  const int total = n * 22;
  const int idx = blockIdx.x * 256 + threadIdx.x;
  if (idx >= total) return;

  float w[9];
#pragma unroll
  for (int t = 0; t < 9; ++t) w[t] = sw[t];

  if (idx < n9) {
    const int p = idx / 9, ch = idx - 9 * p;
    const int py = p / W, px = p - py * W;
    float acc = 0.0f;
#pragma unroll
    for (int dy = -1; dy <= 1; ++dy) {
      int yy = py + dy; yy = yy < 0 ? 0 : (yy >= H ? H - 1 : yy);
#pragma unroll
      for (int dx = -1; dx <= 1; ++dx) {
        int xx = px + dx; xx = xx < 0 ? 0 : (xx >= W ? W - 1 : xx);
        acc += w[(dy + 1) * 3 + (dx + 1)] * f4[(size_t)(yy * W + xx) * 9 + ch];
      }
    }
    nb4[idx] = acc;
  } else {
    const int j = idx - n9;
    const int p = j / 13, ch = j - 13 * p;
    const int py = p / W, px = p - py * W;
    float acc = 0.0f;
#pragma unroll
    for (int dy = -1; dy <= 1; ++dy) {
      int yy = py + dy; yy = yy < 0 ? 0 : (yy >= H ? H - 1 : yy);
#pragma unroll
      for (int dx = -1; dx <= 1; ++dx) {
        int xx = px + dx; xx = xx < 0 ? 0 : (xx >= W ? W - 1 : xx);
        acc += w[(dy + 1) * 3 + (dx + 1)] * f6[(size_t)(yy * W + xx) * 13 + ch];
      }
    }
    nb6[j] = acc;
  }
}

// ============================================================================
// Kernel 2: per-pixel CG contraction + epilogue. Pure streaming: 44 private
// coalesced loads up front, then an uninterrupted unrolled VALU stream.
// No LDS, no barrier -> no lockstep stalls.
// ============================================================================
__global__ __launch_bounds__(256) void cgc_kernel(
    const float* __restrict__ f4, const float* __restrict__ f6,
    const float* __restrict__ nb4, const float* __restrict__ nb6,
    const float* __restrict__ tpw,
    const int* __restrict__ Hp, const int* __restrict__ Wp,
    float* __restrict__ out) {
  const int H = Hp[0], W = Wp[0];
  const int n = H * W;
  const int p = blockIdx.x * 256 + threadIdx.x;
  if (p >= n) return;

  float x4[9], x6[13], y4[9], y6[13];
  {
    const float* a = f4 + (size_t)p * 9;
#pragma unroll
    for (int c = 0; c < 9; ++c) x4[c] = a[c];
    const float* b = f6 + (size_t)p * 13;
#pragma unroll
    for (int c = 0; c < 13; ++c) x6[c] = b[c];
    const float* cy = nb4 + (size_t)p * 9;
#pragma unroll
    for (int c = 0; c < 9; ++c) y4[c] = cy[c];
    const float* d = nb6 + (size_t)p * 13;
#pragma unroll
    for (int c = 0; c < 13; ++c) y6[c] = d[c];
  }

  float t4[4][9];
  float t6[4][13];
#pragma unroll
  for (int pth = 0; pth < 4; ++pth) {
#pragma unroll
    for (int k = 0; k < 9; ++k) t4[pth][k] = 0.0f;
#pragma unroll
    for (int k = 0; k < 13; ++k) t6[pth][k] = 0.0f;
  }

  cg::cg_apply<cg::Tag444>(x4, y4, t4[0]);
  cg::cg_apply<cg::Tag446>(x4, y4, t6[0]);
  cg::cg_apply<cg::Tag464>(x4, y6, t4[1]);
  cg::cg_apply<cg::Tag466>(x4, y6, t6[1]);
  cg::cg_apply<cg::Tag644>(x6, y4, t4[2]);
  cg::cg_apply<cg::Tag646>(x6, y4, t6[2]);
  cg::cg_apply<cg::Tag664>(x6, y6, t4[3]);
  cg::cg_apply<cg::Tag666>(x6, y6, t6[3]);

  const float A4 = 1.5f;                   // sqrt(9/4)
  const float A6 = 1.8027756377319946f;    // sqrt(13/4)

  float o4r[36];
  float o6r[52];
#pragma unroll
  for (int c = 0; c < 4; ++c) {
    const float w40 = tpw[c * 8 + 0], w41 = tpw[c * 8 + 1];
    const float w42 = tpw[c * 8 + 2], w43 = tpw[c * 8 + 3];
    const float w60 = tpw[c * 8 + 4], w61 = tpw[c * 8 + 5];
    const float w62 = tpw[c * 8 + 6], w63 = tpw[c * 8 + 7];
#pragma unroll
    for (int k = 0; k < 9; ++k) {
      const float v = A4 * (w40 * t4[0][k] + w41 * t4[1][k] +
                            w42 * t4[2][k] + w43 * t4[3][k]);
      const int flat = c * 22 + k;
      if (flat < 36) o4r[flat] = v;
      else           o6r[flat - 36] = v;
    }
#pragma unroll
    for (int k = 0; k < 13; ++k) {
      const float v = A6 * (w60 * t6[0][k] + w61 * t6[1][k] +
                            w62 * t6[2][k] + w63 * t6[3][k]);
      const int flat = c * 22 + 9 + k;
      if (flat < 36) o4r[flat] = v;
      else           o6r[flat - 36] = v;
    }
  }
#pragma unroll
  for (int j = 0; j < 36; ++j) o4r[j] += x4[j % 9];
#pragma unroll
  for (int j = 0; j < 52; ++j) o6r[j] += x6[j % 13];

  float* __restrict__ o4p = out + (size_t)p * 36;                   // 144B rows
  float* __restrict__ o6p = out + (size_t)n * 36 + (size_t)p * 52;  // 208B rows
#pragma unroll
  for (int q = 0; q < 9; ++q) {
    float4 v; v.x = o4r[4*q+0]; v.y = o4r[4*q+1]; v.z = o4r[4*q+2]; v.w = o4r[4*q+3];
    reinterpret_cast<float4*>(o4p)[q] = v;
  }
#pragma unroll
  for (int q = 0; q < 13; ++q) {
    float4 v; v.x = o6r[4*q+0]; v.y = o6r[4*q+1]; v.z = o6r[4*q+2]; v.w = o6r[4*q+3];
    reinterpret_cast<float4*>(o6p)[q] = v;
  }
}

// ============================================================================
// Fallback: fused single kernel (round-1 structure), used only if d_ws is too
// small for the nb intermediate. Known-correct at ~177 us.
// ============================================================================
__global__ __launch_bounds__(256) void fused_kernel(
    const float* __restrict__ f4, const float* __restrict__ f6,
    const float* __restrict__ sw, const float* __restrict__ tpw,
    const int* __restrict__ Hp, const int* __restrict__ Wp,
    float* __restrict__ out) {
  const int H = Hp[0], W = Wp[0];
  const int n = H * W;
  const int p = blockIdx.x * 256 + threadIdx.x;
  if (p >= n) return;
  const int py = p / W;
  const int px = p - py * W;

  float x4[9], x6[13];
  {
    const float* b4 = f4 + (size_t)p * 9;
#pragma unroll
    for (int c = 0; c < 9; ++c) x4[c] = b4[c];
    const float* b6 = f6 + (size_t)p * 13;
#pragma unroll
    for (int c = 0; c < 13; ++c) x6[c] = b6[c];
  }
  float w[9];
#pragma unroll
  for (int t = 0; t < 9; ++t) w[t] = sw[t];

  float y4[9], y6[13];
#pragma unroll
  for (int c = 0; c < 9; ++c) y4[c] = w[4] * x4[c];
#pragma unroll
  for (int c = 0; c < 13; ++c) y6[c] = w[4] * x6[c];
#pragma unroll
  for (int dy = -1; dy <= 1; ++dy) {
#pragma unroll
    for (int dx = -1; dx <= 1; ++dx) {
      if (dy == 0 && dx == 0) continue;
      int yy = py + dy; yy = yy < 0 ? 0 : (yy >= H ? H - 1 : yy);
      int xx = px + dx; xx = xx < 0 ? 0 : (xx >= W ? W - 1 : xx);
      const int q = yy * W + xx;
      const float wt = w[(dy + 1) * 3 + (dx + 1)];
      const float* b4 = f4 + (size_t)q * 9;
#pragma unroll
      for (int c = 0; c < 9; ++c) y4[c] += wt * b4[c];
      const float* b6 = f6 + (size_t)q * 13;
#pragma unroll
      for (int c = 0; c < 13; ++c) y6[c] += wt * b6[c];
    }
  }

  float t4[4][9];
  float t6[4][13];
#pragma unroll
  for (int pth = 0; pth < 4; ++pth) {
#pragma unroll
    for (int k = 0; k < 9; ++k) t4[pth][k] = 0.0f;
#pragma unroll
    for (int k = 0; k < 13; ++k) t6[pth][k] = 0.0f;
  }
  cg::cg_apply<cg::Tag444>(x4, y4, t4[0]);
  cg::cg_apply<cg::Tag446>(x4, y4, t6[0]);
  cg::cg_apply<cg::Tag464>(x4, y6, t4[1]);
  cg::cg_apply<cg::Tag466>(x4, y6, t6[1]);
  cg::cg_apply<cg::Tag644>(x6, y4, t4[2]);
  cg::cg_apply<cg::Tag646>(x6, y4, t6[2]);
  cg::cg_apply<cg::Tag664>(x6, y6, t4[3]);
  cg::cg_apply<cg::Tag666>(x6, y6, t6[3]);

  const float A4 = 1.5f;
  const float A6 = 1.8027756377319946f;
  float o4r[36];
  float o6r[52];
#pragma unroll
  for (int c = 0; c < 4; ++c) {
    const float w40 = tpw[c * 8 + 0], w41 = tpw[c * 8 + 1];
    const float w42 = tpw[c * 8 + 2], w43 = tpw[c * 8 + 3];
    const float w60 = tpw[c * 8 + 4], w61 = tpw[c * 8 + 5];
    const float w62 = tpw[c * 8 + 6], w63 = tpw[c * 8 + 7];
#pragma unroll
    for (int k = 0; k < 9; ++k) {
      const float v = A4 * (w40 * t4[0][k] + w41 * t4[1][k] +
                            w42 * t4[2][k] + w43 * t4[3][k]);
      const int flat = c * 22 + k;
      if (flat < 36) o4r[flat] = v;
      else           o6r[flat - 36] = v;
    }
#pragma unroll
    for (int k = 0; k < 13; ++k) {
      const float v = A6 * (w60 * t6[0][k] + w61 * t6[1][k] +
                            w62 * t6[2][k] + w63 * t6[3][k]);
      const int flat = c * 22 + 9 + k;
      if (flat < 36) o4r[flat] = v;
      else           o6r[flat - 36] = v;
    }
  }
#pragma unroll
  for (int j = 0; j < 36; ++j) o4r[j] += x4[j % 9];
#pragma unroll
  for (int j = 0; j < 52; ++j) o6r[j] += x6[j % 13];

  float* __restrict__ o4p = out + (size_t)p * 36;
  float* __restrict__ o6p = out + (size_t)n * 36 + (size_t)p * 52;
#pragma unroll
  for (int q = 0; q < 9; ++q) {
    float4 v; v.x = o4r[4*q+0]; v.y = o4r[4*q+1]; v.z = o4r[4*q+2]; v.w = o4r[4*q+3];
    reinterpret_cast<float4*>(o4p)[q] = v;
  }
#pragma unroll
  for (int q = 0; q < 13; ++q) {
    float4 v; v.x = o6r[4*q+0]; v.y = o6r[4*q+1]; v.z = o6r[4*q+2]; v.w = o6r[4*q+3];
    reinterpret_cast<float4*>(o6p)[q] = v;
  }
}

extern "C" void kernel_launch(void* const* d_in, const int* in_sizes, int n_in,
                              void* d_out, int out_size, void* d_ws, size_t ws_size,
                              hipStream_t stream) {
  const float* f4  = (const float*)d_in[0];
  const float* f6  = (const float*)d_in[1];
  const float* sw  = (const float*)d_in[2];
  const float* tpw = (const float*)d_in[3];
  const int*   Hp  = (const int*)d_in[4];
  const int*   Wp  = (const int*)d_in[5];
  float* out = (float*)d_out;

  const int n = in_sizes[0] / 9;  // H*W
  const size_t need = (size_t)n * 22 * sizeof(float);

  if (ws_size >= need) {
    float* nb4 = (float*)d_ws;
    float* nb6 = nb4 + (size_t)n * 9;
    const int convBlocks = (n * 22 + 255) / 256;
    conv_kernel<<<dim3(convBlocks), dim3(256), 0, stream>>>(
        f4, f6, sw, Hp, Wp, nb4, nb6);
    const int cgBlocks = (n + 255) / 256;
    cgc_kernel<<<dim3(cgBlocks), dim3(256), 0, stream>>>(
        f4, f6, nb4, nb6, tpw, Hp, Wp, out);
  } else {
    const int blocks = (n + 255) / 256;
    fused_kernel<<<dim3(blocks), dim3(256), 0, stream>>>(
        f4, f6, sw, tpw, Hp, Wp, out);
  }
}